// Round 4
// baseline (577.761 us; speedup 1.0000x reference)
//
#include <hip/hip_runtime.h>

typedef unsigned short u16;
typedef unsigned int u32;
typedef __bf16 bf16x8 __attribute__((ext_vector_type(8)));
typedef float f32x4 __attribute__((ext_vector_type(4)));

// Problem constants: B=4, N=2048, C=2048, H=16, DH=128
// tokens BN = 8192, qkv row = 3*C = 6144

__device__ __forceinline__ u16 f2bf(float f) {
    u32 u = __builtin_bit_cast(u32, f);
    u += 0x7FFFu + ((u >> 16) & 1u);   // round-to-nearest-even
    return (u16)(u >> 16);
}
__device__ __forceinline__ float bf2f(u16 h) {
    return __builtin_bit_cast(float, ((u32)h) << 16);
}

// ---------------- fp32 -> bf16 conversion (vectorized) ----------------
__global__ __launch_bounds__(256) void cvt_bf16(const float* __restrict__ in,
                                                u16* __restrict__ out, int n4) {
    int i = blockIdx.x * 256 + threadIdx.x;
    if (i >= n4) return;
    const float4 f = reinterpret_cast<const float4*>(in)[i];
    ushort4 o;
    o.x = f2bf(f.x); o.y = f2bf(f.y); o.z = f2bf(f.z); o.w = f2bf(f.w);
    reinterpret_cast<ushort4*>(out)[i] = o;
}

// ---------------- async global->LDS copy, 16 B per lane ----------------
typedef const __attribute__((address_space(1))) void* gas1_t;
typedef __attribute__((address_space(3))) void* las3_t;
__device__ __forceinline__ void cp16(const void* g, void* l) {
    __builtin_amdgcn_global_load_lds((gas1_t)g, (las3_t)l, 16, 0, 0);
}

// ---------------- bf16 NT GEMM: C = A(MxK) * B(NxK)^T + bias ----------------
// 256x128 block tile, BK=32, 256 threads = 4 waves stacked in M; each wave owns
// a 64x128 strip (4x8 MFMA tiles, 32 MFMA/iter -> 2x the MFMA-per-barrier of the
// 128x128 version, and A-tile rows are read by exactly one wave: LDS read
// bytes/FLOP down 25%).
// LDS k-chunk XOR swizzle (row r chunk q at slot q^((r>>1)&3)): 0 bank conflicts.
// Double-buffered: next tile's global_load_lds issued before computing current.
template <int OUT_BF16>
__global__ __launch_bounds__(256) void gemm_nt(const u16* __restrict__ A,
                                               const u16* __restrict__ Bm,
                                               const float* __restrict__ bias,
                                               void* __restrict__ Cout,
                                               int M, int N, int K) {
    __shared__ __align__(16) u16 lA[2][256 * 32];
    __shared__ __align__(16) u16 lB[2][128 * 32];

    const int tid  = threadIdx.x;
    const int lane = tid & 63;
    const int wave = tid >> 6;
    const int wm   = wave * 64;        // wave row strip in tile
    const int quad = lane >> 4;        // 0..3
    const int r16  = lane & 15;

    const long bm = (long)blockIdx.y * 256;
    const long bn = (long)blockIdx.x * 128;

    f32x4 acc[4][8];
    const f32x4 zero = {0.f, 0.f, 0.f, 0.f};
#pragma unroll
    for (int i = 0; i < 4; ++i)
#pragma unroll
        for (int j = 0; j < 8; ++j) acc[i][j] = zero;

    // staging: thread t owns LDS chunk t (row = t>>2, slot = t&3); loads global
    // k-chunk q = slot ^ ((row>>1)&3).  (row+64k keeps the same XOR term.)
    const int srow = tid >> 2;
    const int sq   = (tid & 3) ^ ((srow >> 1) & 3);
    const u16* ga = A  + (bm + srow) * (long)K + sq * 8;
    const u16* gb = Bm + (bn + srow) * (long)K + sq * 8;
    const long rK64 = 64 * (long)K;

    // read-side swizzle factor (uniform inside the unrolled loops)
    const int qxr = quad ^ ((r16 >> 1) & 3);

    // prologue: stage tile 0 into buffer 0
    {
        u16* la = &lA[0][tid * 8];
        u16* lb = &lB[0][tid * 8];
        cp16(ga, la);
        cp16(ga + rK64, la + 64 * 32);
        cp16(ga + 2 * rK64, la + 128 * 32);
        cp16(ga + 3 * rK64, la + 192 * 32);
        cp16(gb, lb);
        cp16(gb + rK64, lb + 64 * 32);
    }
    __syncthreads();

    int cur = 0;
    for (int k0 = 32; k0 < K; k0 += 32) {
        // issue loads for the NEXT tile into the other buffer (no wait yet)
        {
            u16* la = &lA[cur ^ 1][tid * 8];
            u16* lb = &lB[cur ^ 1][tid * 8];
            cp16(ga + k0, la);
            cp16(ga + k0 + rK64, la + 64 * 32);
            cp16(ga + k0 + 2 * rK64, la + 128 * 32);
            cp16(ga + k0 + 3 * rK64, la + 192 * 32);
            cp16(gb + k0, lb);
            cp16(gb + k0 + rK64, lb + 64 * 32);
        }

        // compute current tile from buffer `cur`
        const u16* cA = lA[cur];
        const u16* cB = lB[cur];
        bf16x8 af[4], bf[8];
#pragma unroll
        for (int t = 0; t < 4; ++t)
            af[t] = *reinterpret_cast<const bf16x8*>(&cA[(wm + t * 16 + r16) * 32 + qxr * 8]);
#pragma unroll
        for (int t = 0; t < 8; ++t)
            bf[t] = *reinterpret_cast<const bf16x8*>(&cB[(t * 16 + r16) * 32 + qxr * 8]);

#pragma unroll
        for (int i = 0; i < 4; ++i)
#pragma unroll
            for (int j = 0; j < 8; ++j)
                acc[i][j] = __builtin_amdgcn_mfma_f32_16x16x32_bf16(af[i], bf[j], acc[i][j], 0, 0, 0);

        // single barrier: drains next-tile loads (issued ~32 MFMA ago) and
        // guarantees everyone is done ds_reading the buffer we overwrite next.
        __syncthreads();
        cur ^= 1;
    }

    // final tile
    {
        const u16* cA = lA[cur];
        const u16* cB = lB[cur];
        bf16x8 af[4], bf[8];
#pragma unroll
        for (int t = 0; t < 4; ++t)
            af[t] = *reinterpret_cast<const bf16x8*>(&cA[(wm + t * 16 + r16) * 32 + qxr * 8]);
#pragma unroll
        for (int t = 0; t < 8; ++t)
            bf[t] = *reinterpret_cast<const bf16x8*>(&cB[(t * 16 + r16) * 32 + qxr * 8]);
#pragma unroll
        for (int i = 0; i < 4; ++i)
#pragma unroll
            for (int j = 0; j < 8; ++j)
                acc[i][j] = __builtin_amdgcn_mfma_f32_16x16x32_bf16(af[i], bf[j], acc[i][j], 0, 0, 0);
    }

    // epilogue: C/D layout col = lane&15, row = quad*4 + reg
#pragma unroll
    for (int j = 0; j < 8; ++j) {
        const long col = bn + j * 16 + r16;
        const float bc = bias[col];
#pragma unroll
        for (int i = 0; i < 4; ++i) {
#pragma unroll
            for (int r = 0; r < 4; ++r) {
                const long row = bm + wm + i * 16 + quad * 4 + r;
                float v = acc[i][j][r] + bc;
                if (OUT_BF16)
                    ((u16*)Cout)[row * (long)N + col] = f2bf(v);
                else
                    ((float*)Cout)[row * (long)N + col] = v;
            }
        }
    }
}

// ---------------- per-token head-mixing attention ----------------
// One block (256 thr) per token. q,k,v: 16x128 each from qkv row (3*2048 bf16).
// S = q k^T / sqrt(2048) (16x16), softmax rows, O = S v (16x128).
// Write O to scrambled layout: row h*128 + n/16, col (n%16)*128 + d (bf16).
__global__ __launch_bounds__(256) void attn(const u16* __restrict__ qkv,
                                            u16* __restrict__ outb) {
    __shared__ float sQ[16 * 132];   // +4 pad: stride 132 floats kills bank conflicts
    __shared__ float sK[16 * 132];
    __shared__ float sV[16 * 132];
    __shared__ float sP[16 * 17];

    const int tid = threadIdx.x;
    const int token = blockIdx.x;
    const int b = token >> 11;      // /2048
    const int n = token & 2047;
    const u16* row = qkv + (long)token * 6144;

    // ---- load q,k,v -> LDS as fp32 (each thread: 8 contiguous elems) ----
    {
        const int r  = tid >> 4;          // 0..15
        const int c8 = (tid & 15) * 8;    // 0,8,...,120
#pragma unroll
        for (int m = 0; m < 3; ++m) {
            const uint4 u = *reinterpret_cast<const uint4*>(row + m * 2048 + tid * 8);
            float* dst = (m == 0 ? sQ : (m == 1 ? sK : sV)) + r * 132 + c8;
            float4 lo, hi;
            lo.x = bf2f((u16)u.x); lo.y = bf2f((u16)(u.x >> 16));
            lo.z = bf2f((u16)u.y); lo.w = bf2f((u16)(u.y >> 16));
            hi.x = bf2f((u16)u.z); hi.y = bf2f((u16)(u.z >> 16));
            hi.z = bf2f((u16)u.w); hi.w = bf2f((u16)(u.w >> 16));
            *reinterpret_cast<float4*>(dst)     = lo;
            *reinterpret_cast<float4*>(dst + 4) = hi;
        }
    }
    __syncthreads();

    // ---- S + softmax: thread (h,g) = (tid>>4, tid&15); 16-lane-group reductions ----
    {
        const int h = tid >> 4, g = tid & 15;
        const float4* qr = reinterpret_cast<const float4*>(&sQ[h * 132]);
        const float4* kr = reinterpret_cast<const float4*>(&sK[g * 132]);
        float s = 0.f;
#pragma unroll
        for (int d = 0; d < 32; ++d) {
            const float4 a = qr[d], k4 = kr[d];
            s += a.x * k4.x + a.y * k4.y + a.z * k4.z + a.w * k4.w;
        }
        s *= 0.022097086912079608f;   // 1/sqrt(2048)
        float mx = s;
#pragma unroll
        for (int o = 8; o >= 1; o >>= 1) mx = fmaxf(mx, __shfl_xor(mx, o, 16));
        const float e = __expf(s - mx);
        float sum = e;
#pragma unroll
        for (int o = 8; o >= 1; o >>= 1) sum += __shfl_xor(sum, o, 16);
        sP[h * 17 + g] = e / sum;
    }
    __syncthreads();

    // ---- O = P @ V; thread (h, dblk) handles d = dblk*8 .. +7 ----
    {
        const int h = tid >> 4, dblk = tid & 15;
        float p[16];
#pragma unroll
        for (int g = 0; g < 16; ++g) p[g] = sP[h * 17 + g];
        float4 o0 = {0.f, 0.f, 0.f, 0.f}, o1 = {0.f, 0.f, 0.f, 0.f};
#pragma unroll
        for (int g = 0; g < 16; ++g) {
            const float* vr = &sV[g * 132 + dblk * 8];
            const float4 v0 = *reinterpret_cast<const float4*>(vr);
            const float4 v1 = *reinterpret_cast<const float4*>(vr + 4);
            o0.x += p[g] * v0.x; o0.y += p[g] * v0.y; o0.z += p[g] * v0.z; o0.w += p[g] * v0.w;
            o1.x += p[g] * v1.x; o1.y += p[g] * v1.y; o1.z += p[g] * v1.z; o1.w += p[g] * v1.w;
        }
        // scrambled reshape target: row = h*128 + n/16, col = (n%16)*128 + d
        const long rr = (long)h * 128 + (n >> 4);
        const long cc = (long)(n & 15) * 128 + dblk * 8;
        u16* dst = outb + ((long)b * 2048 + rr) * 2048 + cc;
        uint4 pk;
        pk.x = (u32)f2bf(o0.x) | ((u32)f2bf(o0.y) << 16);
        pk.y = (u32)f2bf(o0.z) | ((u32)f2bf(o0.w) << 16);
        pk.z = (u32)f2bf(o1.x) | ((u32)f2bf(o1.y) << 16);
        pk.w = (u32)f2bf(o1.z) | ((u32)f2bf(o1.w) << 16);
        *reinterpret_cast<uint4*>(dst) = pk;
    }
}

// ---------------- launch ----------------
extern "C" void kernel_launch(void* const* d_in, const int* in_sizes, int n_in,
                              void* d_out, int out_size, void* d_ws, size_t ws_size,
                              hipStream_t stream) {
    const float* x     = (const float*)d_in[0];   // (4,2048,2048)
    const float* w_qkv = (const float*)d_in[1];   // (6144,2048)
    const float* b_qkv = (const float*)d_in[2];   // (6144,)
    const float* w_out = (const float*)d_in[3];   // (2048,2048)
    const float* b_out = (const float*)d_in[4];   // (2048,)
    float* out = (float*)d_out;                   // (4,2048,2048) fp32

    char* ws = (char*)d_ws;
    // workspace layout (bytes):
    //   xb    @ 0          : 8192*2048*2  = 33554432
    //   wqkvb @ 33554432   : 6144*2048*2  = 25165824
    //   woutb @ 58720256   : 2048*2048*2  =  8388608
    //   qkvb  @ 67108864   : 8192*6144*2  = 100663296   (end 167772160)
    //   attnb aliases xb (x no longer needed after GEMM1)
    u16* xb    = (u16*)(ws);
    u16* wqkvb = (u16*)(ws + 33554432);
    u16* woutb = (u16*)(ws + 58720256);
    u16* qkvb  = (u16*)(ws + 67108864);
    u16* attnb = xb;

    cvt_bf16<<<16384, 256, 0, stream>>>(x,     xb,    16777216 / 4);
    cvt_bf16<<<12288, 256, 0, stream>>>(w_qkv, wqkvb, 12582912 / 4);
    cvt_bf16<<<4096,  256, 0, stream>>>(w_out, woutb, 4194304 / 4);

    dim3 g1(48, 32);  // N/128, M/256
    gemm_nt<1><<<g1, 256, 0, stream>>>(xb, wqkvb, b_qkv, qkvb, 8192, 6144, 2048);

    attn<<<8192, 256, 0, stream>>>(qkvb, attnb);

    dim3 g2(16, 32);  // N/128, M/256
    gemm_nt<0><<<g2, 256, 0, stream>>>(attnb, woutb, b_out, out, 8192, 2048, 2048);
}

// Round 5
// 541.286 us; speedup vs baseline: 1.0674x; 1.0674x over previous
//
#include <hip/hip_runtime.h>

typedef unsigned short u16;
typedef unsigned int u32;
typedef __bf16 bf16x8 __attribute__((ext_vector_type(8)));
typedef float f32x4 __attribute__((ext_vector_type(4)));
typedef float f32x16 __attribute__((ext_vector_type(16)));

// Problem constants: B=4, N=2048, C=2048, H=16, DH=128
// tokens BN = 8192, qkv row = 3*C = 6144

__device__ __forceinline__ u16 f2bf(float f) {
    u32 u = __builtin_bit_cast(u32, f);
    u += 0x7FFFu + ((u >> 16) & 1u);   // round-to-nearest-even
    return (u16)(u >> 16);
}
__device__ __forceinline__ float bf2f(u16 h) {
    return __builtin_bit_cast(float, ((u32)h) << 16);
}

// ---------------- fp32 -> bf16 conversion (vectorized) ----------------
__global__ __launch_bounds__(256) void cvt_bf16(const float* __restrict__ in,
                                                u16* __restrict__ out, int n4) {
    int i = blockIdx.x * 256 + threadIdx.x;
    if (i >= n4) return;
    const float4 f = reinterpret_cast<const float4*>(in)[i];
    ushort4 o;
    o.x = f2bf(f.x); o.y = f2bf(f.y); o.z = f2bf(f.z); o.w = f2bf(f.w);
    reinterpret_cast<ushort4*>(out)[i] = o;
}

// ---------------- async global->LDS copy, 16 B per lane ----------------
typedef const __attribute__((address_space(1))) void* gas1_t;
typedef __attribute__((address_space(3))) void* las3_t;
__device__ __forceinline__ void cp16(const void* g, void* l) {
    __builtin_amdgcn_global_load_lds((gas1_t)g, (las3_t)l, 16, 0, 0);
}

// ---------------- bf16 NT GEMM: C = A(MxK) * B(NxK)^T + bias ----------------
// 128x128 block tile, BK=32, 256 threads (4 waves as 2x2, each wave 64x64).
// MFMA 32x32x16: 8 MFMA/iter (vs 16 for 16x16x32) -> half the MFMA issue slots
// competing with VALU on the issue port, better pipe rate (2382 vs 2075 TF).
// Wave tile = 2x2 of 32x32, 2 k-steps per BK=32. acc = 4 x 16 = 64 AGPR (same).
// LDS k-chunk XOR swizzle (row r chunk q at slot q^((r>>1)&3)): 0 bank conflicts.
// Double-buffered: next tile's global_load_lds issued before computing current.
template <int OUT_BF16>
__global__ __launch_bounds__(256) void gemm_nt(const u16* __restrict__ A,
                                               const u16* __restrict__ Bm,
                                               const float* __restrict__ bias,
                                               void* __restrict__ Cout,
                                               int M, int N, int K) {
    __shared__ __align__(16) u16 lA[2][128 * 32];
    __shared__ __align__(16) u16 lB[2][128 * 32];

    const int tid  = threadIdx.x;
    const int lane = tid & 63;
    const int wave = tid >> 6;
    const int wm   = (wave >> 1) * 64;  // wave row offset in tile
    const int wn   = (wave & 1) * 64;   // wave col offset in tile
    const int r32  = lane & 31;
    const int half = lane >> 5;         // 0..1

    const long bm = (long)blockIdx.y * 128;
    const long bn = (long)blockIdx.x * 128;

    f32x16 acc[2][2];
#pragma unroll
    for (int i = 0; i < 2; ++i)
#pragma unroll
        for (int j = 0; j < 2; ++j)
#pragma unroll
            for (int r = 0; r < 16; ++r) acc[i][j][r] = 0.f;

    // staging: thread t owns LDS chunk t (row = t>>2, slot = t&3); loads global
    // k-chunk q = slot ^ ((row>>1)&3).  (row+64 has the same XOR term.)
    const int srow = tid >> 2;
    const int sq   = (tid & 3) ^ ((srow >> 1) & 3);
    const u16* ga = A  + (bm + srow) * (long)K + sq * 8;
    const u16* gb = Bm + (bn + srow) * (long)K + sq * 8;
    u16* la0 = &lA[0][tid * 8];
    u16* lb0 = &lB[0][tid * 8];
    u16* la1 = &lA[1][tid * 8];
    u16* lb1 = &lB[1][tid * 8];
    const long hK = 64 * (long)K;

    // read-side swizzle factor: row = (multiple of 32) + r32 -> xr dep. on r32 only
    const int xr = (r32 >> 1) & 3;
    // chunk for k-step ks: q = (ks*2 + half) ^ xr   (element offset q*8)
    const int q0 = (0 + half) ^ xr;   // ks=0
    const int q1 = (2 + half) ^ xr;   // ks=1

    // prologue: stage tile 0 into buffer 0
    cp16(ga, la0);
    cp16(ga + hK, la0 + 64 * 32);
    cp16(gb, lb0);
    cp16(gb + hK, lb0 + 64 * 32);
    __syncthreads();

    int cur = 0;
    for (int k0 = 32; k0 < K; k0 += 32) {
        // issue loads for the NEXT tile into the other buffer (no wait yet)
        u16* la = cur ? la0 : la1;
        u16* lb = cur ? lb0 : lb1;
        cp16(ga + k0, la);
        cp16(ga + k0 + hK, la + 64 * 32);
        cp16(gb + k0, lb);
        cp16(gb + k0 + hK, lb + 64 * 32);

        // compute current tile from buffer `cur`
        const u16* cA = lA[cur];
        const u16* cB = lB[cur];
        bf16x8 af[2][2], bf[2][2];   // [m or n tile][k-step]
#pragma unroll
        for (int t = 0; t < 2; ++t) {
            const int rowA = (wm + t * 32 + r32) * 32;
            const int rowB = (wn + t * 32 + r32) * 32;
            af[t][0] = *reinterpret_cast<const bf16x8*>(&cA[rowA + q0 * 8]);
            af[t][1] = *reinterpret_cast<const bf16x8*>(&cA[rowA + q1 * 8]);
            bf[t][0] = *reinterpret_cast<const bf16x8*>(&cB[rowB + q0 * 8]);
            bf[t][1] = *reinterpret_cast<const bf16x8*>(&cB[rowB + q1 * 8]);
        }

#pragma unroll
        for (int ks = 0; ks < 2; ++ks)
#pragma unroll
            for (int i = 0; i < 2; ++i)
#pragma unroll
                for (int j = 0; j < 2; ++j)
                    acc[i][j] = __builtin_amdgcn_mfma_f32_32x32x16_bf16(af[i][ks], bf[j][ks], acc[i][j], 0, 0, 0);

        // single barrier: drains next-tile loads and protects the buffer we
        // overwrite next iteration.
        __syncthreads();
        cur ^= 1;
    }

    // final tile
    {
        const u16* cA = lA[cur];
        const u16* cB = lB[cur];
        bf16x8 af[2][2], bf[2][2];
#pragma unroll
        for (int t = 0; t < 2; ++t) {
            const int rowA = (wm + t * 32 + r32) * 32;
            const int rowB = (wn + t * 32 + r32) * 32;
            af[t][0] = *reinterpret_cast<const bf16x8*>(&cA[rowA + q0 * 8]);
            af[t][1] = *reinterpret_cast<const bf16x8*>(&cA[rowA + q1 * 8]);
            bf[t][0] = *reinterpret_cast<const bf16x8*>(&cB[rowB + q0 * 8]);
            bf[t][1] = *reinterpret_cast<const bf16x8*>(&cB[rowB + q1 * 8]);
        }
#pragma unroll
        for (int ks = 0; ks < 2; ++ks)
#pragma unroll
            for (int i = 0; i < 2; ++i)
#pragma unroll
                for (int j = 0; j < 2; ++j)
                    acc[i][j] = __builtin_amdgcn_mfma_f32_32x32x16_bf16(af[i][ks], bf[j][ks], acc[i][j], 0, 0, 0);
    }

    // epilogue: 32x32 C/D layout: col = lane&31, row = (reg&3) + 8*(reg>>2) + 4*(lane>>5)
#pragma unroll
    for (int j = 0; j < 2; ++j) {
        const long col = bn + wn + j * 32 + r32;
        const float bc = bias[col];
#pragma unroll
        for (int i = 0; i < 2; ++i) {
#pragma unroll
            for (int reg = 0; reg < 16; ++reg) {
                const long row = bm + wm + i * 32 + (reg & 3) + 8 * (reg >> 2) + 4 * half;
                float v = acc[i][j][reg] + bc;
                if (OUT_BF16)
                    ((u16*)Cout)[row * (long)N + col] = f2bf(v);
                else
                    ((float*)Cout)[row * (long)N + col] = v;
            }
        }
    }
}

// ---------------- per-token head-mixing attention ----------------
// One block (256 thr) per token. q,k,v: 16x128 each from qkv row (3*2048 bf16).
// S = q k^T / sqrt(2048) (16x16), softmax rows, O = S v (16x128).
// Write O to scrambled layout: row h*128 + n/16, col (n%16)*128 + d (bf16).
__global__ __launch_bounds__(256) void attn(const u16* __restrict__ qkv,
                                            u16* __restrict__ outb) {
    __shared__ float sQ[16 * 132];   // +4 pad: stride 132 floats kills bank conflicts
    __shared__ float sK[16 * 132];
    __shared__ float sV[16 * 132];
    __shared__ float sP[16 * 17];

    const int tid = threadIdx.x;
    const int token = blockIdx.x;
    const int b = token >> 11;      // /2048
    const int n = token & 2047;
    const u16* row = qkv + (long)token * 6144;

    // ---- load q,k,v -> LDS as fp32 (each thread: 8 contiguous elems) ----
    {
        const int r  = tid >> 4;          // 0..15
        const int c8 = (tid & 15) * 8;    // 0,8,...,120
#pragma unroll
        for (int m = 0; m < 3; ++m) {
            const uint4 u = *reinterpret_cast<const uint4*>(row + m * 2048 + tid * 8);
            float* dst = (m == 0 ? sQ : (m == 1 ? sK : sV)) + r * 132 + c8;
            float4 lo, hi;
            lo.x = bf2f((u16)u.x); lo.y = bf2f((u16)(u.x >> 16));
            lo.z = bf2f((u16)u.y); lo.w = bf2f((u16)(u.y >> 16));
            hi.x = bf2f((u16)u.z); hi.y = bf2f((u16)(u.z >> 16));
            hi.z = bf2f((u16)u.w); hi.w = bf2f((u16)(u.w >> 16));
            *reinterpret_cast<float4*>(dst)     = lo;
            *reinterpret_cast<float4*>(dst + 4) = hi;
        }
    }
    __syncthreads();

    // ---- S + softmax: thread (h,g) = (tid>>4, tid&15); 16-lane-group reductions ----
    {
        const int h = tid >> 4, g = tid & 15;
        const float4* qr = reinterpret_cast<const float4*>(&sQ[h * 132]);
        const float4* kr = reinterpret_cast<const float4*>(&sK[g * 132]);
        float s = 0.f;
#pragma unroll
        for (int d = 0; d < 32; ++d) {
            const float4 a = qr[d], k4 = kr[d];
            s += a.x * k4.x + a.y * k4.y + a.z * k4.z + a.w * k4.w;
        }
        s *= 0.022097086912079608f;   // 1/sqrt(2048)
        float mx = s;
#pragma unroll
        for (int o = 8; o >= 1; o >>= 1) mx = fmaxf(mx, __shfl_xor(mx, o, 16));
        const float e = __expf(s - mx);
        float sum = e;
#pragma unroll
        for (int o = 8; o >= 1; o >>= 1) sum += __shfl_xor(sum, o, 16);
        sP[h * 17 + g] = e / sum;
    }
    __syncthreads();

    // ---- O = P @ V; thread (h, dblk) handles d = dblk*8 .. +7 ----
    {
        const int h = tid >> 4, dblk = tid & 15;
        float p[16];
#pragma unroll
        for (int g = 0; g < 16; ++g) p[g] = sP[h * 17 + g];
        float4 o0 = {0.f, 0.f, 0.f, 0.f}, o1 = {0.f, 0.f, 0.f, 0.f};
#pragma unroll
        for (int g = 0; g < 16; ++g) {
            const float* vr = &sV[g * 132 + dblk * 8];
            const float4 v0 = *reinterpret_cast<const float4*>(vr);
            const float4 v1 = *reinterpret_cast<const float4*>(vr + 4);
            o0.x += p[g] * v0.x; o0.y += p[g] * v0.y; o0.z += p[g] * v0.z; o0.w += p[g] * v0.w;
            o1.x += p[g] * v1.x; o1.y += p[g] * v1.y; o1.z += p[g] * v1.z; o1.w += p[g] * v1.w;
        }
        // scrambled reshape target: row = h*128 + n/16, col = (n%16)*128 + d
        const long rr = (long)h * 128 + (n >> 4);
        const long cc = (long)(n & 15) * 128 + dblk * 8;
        u16* dst = outb + ((long)b * 2048 + rr) * 2048 + cc;
        uint4 pk;
        pk.x = (u32)f2bf(o0.x) | ((u32)f2bf(o0.y) << 16);
        pk.y = (u32)f2bf(o0.z) | ((u32)f2bf(o0.w) << 16);
        pk.z = (u32)f2bf(o1.x) | ((u32)f2bf(o1.y) << 16);
        pk.w = (u32)f2bf(o1.z) | ((u32)f2bf(o1.w) << 16);
        *reinterpret_cast<uint4*>(dst) = pk;
    }
}

// ---------------- launch ----------------
extern "C" void kernel_launch(void* const* d_in, const int* in_sizes, int n_in,
                              void* d_out, int out_size, void* d_ws, size_t ws_size,
                              hipStream_t stream) {
    const float* x     = (const float*)d_in[0];   // (4,2048,2048)
    const float* w_qkv = (const float*)d_in[1];   // (6144,2048)
    const float* b_qkv = (const float*)d_in[2];   // (6144,)
    const float* w_out = (const float*)d_in[3];   // (2048,2048)
    const float* b_out = (const float*)d_in[4];   // (2048,)
    float* out = (float*)d_out;                   // (4,2048,2048) fp32

    char* ws = (char*)d_ws;
    // workspace layout (bytes):
    //   xb    @ 0          : 8192*2048*2  = 33554432
    //   wqkvb @ 33554432   : 6144*2048*2  = 25165824
    //   woutb @ 58720256   : 2048*2048*2  =  8388608
    //   qkvb  @ 67108864   : 8192*6144*2  = 100663296   (end 167772160)
    //   attnb aliases xb (x no longer needed after GEMM1)
    u16* xb    = (u16*)(ws);
    u16* wqkvb = (u16*)(ws + 33554432);
    u16* woutb = (u16*)(ws + 58720256);
    u16* qkvb  = (u16*)(ws + 67108864);
    u16* attnb = xb;

    cvt_bf16<<<16384, 256, 0, stream>>>(x,     xb,    16777216 / 4);
    cvt_bf16<<<12288, 256, 0, stream>>>(w_qkv, wqkvb, 12582912 / 4);
    cvt_bf16<<<4096,  256, 0, stream>>>(w_out, woutb, 4194304 / 4);

    dim3 g1(48, 64);  // N/128, M/128
    gemm_nt<1><<<g1, 256, 0, stream>>>(xb, wqkvb, b_qkv, qkvb, 8192, 6144, 2048);

    attn<<<8192, 256, 0, stream>>>(qkvb, attnb);

    dim3 g2(16, 64);  // N/128, M/128
    gemm_nt<0><<<g2, 256, 0, stream>>>(attnb, woutb, b_out, out, 8192, 2048, 2048);
}